// Round 1
// baseline (518.590 us; speedup 1.0000x reference)
//
#include <hip/hip_runtime.h>

#define Hdim 128
#define Wdim 128
#define Cdim 64
#define COdim 64
#define Bdim 4
#define HW (Hdim*Wdim)

// Static device scratch (avoids dependence on ws_size).
__device__ float  g_wT[576*64];          // wT[k=(c*9+t)][co]
__device__ float4 g_offs[Bdim*Hdim*Wdim]; // (off0, off1, s1, s2) per pixel

__global__ void kt_transpose(const float* __restrict__ weight) {
    int g = blockIdx.x*256 + threadIdx.x;
    if (g < COdim*576) {
        int co = g / 576, k = g % 576;
        g_wT[k*64 + co] = weight[g];
    }
}

__global__ __launch_bounds__(256) void k_offsets(const float* __restrict__ x,
                                                 const float* __restrict__ w_off,
                                                 const float* __restrict__ b_off) {
    int gid = blockIdx.x;          // 0..255 ; 2 rows per block
    int b   = gid >> 6;
    int r   = gid & 63;
    int row = threadIdx.x >> 7;    // 0..1
    int j   = threadIdx.x & 127;
    int i   = r*2 + row;

    float a0 = b_off[0], a1 = b_off[1], a2 = b_off[2], a3 = b_off[3];
    for (int c = 0; c < Cdim; ++c) {
        const float* xb = x + (size_t)(b*Cdim + c)*HW;
        const float* wo = w_off + c*9;
        #pragma unroll
        for (int t = 0; t < 9; ++t) {
            int dy = t/3 - 1, dx = t%3 - 1;
            int yy = i + dy, xx = j + dx;
            float v = 0.f;
            if (yy >= 0 && yy < Hdim && xx >= 0 && xx < Wdim) v = xb[yy*Wdim + xx];
            a0 = fmaf(v, wo[0*Cdim*9 + t], a0);
            a1 = fmaf(v, wo[1*Cdim*9 + t], a1);
            a2 = fmaf(v, wo[2*Cdim*9 + t], a2);
            a3 = fmaf(v, wo[3*Cdim*9 + t], a3);
        }
    }
    float s1 = fmaxf(a2, 0.f) + 1.f;
    float s2 = fmaxf(a3, 0.f) + 1.f;
    g_offs[(b*Hdim + i)*Wdim + j] = make_float4(a0, a1, s1, s2);
}

__global__ __launch_bounds__(256, 4) void k_deform(const float* __restrict__ x,
                                                   const float* __restrict__ bias,
                                                   float* __restrict__ out) {
    __shared__ float lds[64*65];
    int gid  = blockIdx.x;        // 0..1023
    int b    = gid >> 8;
    int r    = gid & 255;
    int i    = r >> 1;
    int j0   = (r & 1) << 6;
    int wid  = threadIdx.x >> 6;  // 0..3 -> c-chunk
    int lane = threadIdx.x & 63;
    int j    = j0 + lane;

    for (int t = threadIdx.x; t < 64*65; t += 256) lds[t] = 0.f;
    __syncthreads();

    float4 o = g_offs[(b*Hdim + i)*Wdim + j];
    float off0 = o.x, off1 = o.y, s1 = o.z, s2 = o.w;

    float acc[64];
    #pragma unroll
    for (int q = 0; q < 64; ++q) acc[q] = 0.f;

    const float* xb = x + (size_t)b*Cdim*HW;
    int c0 = wid * 16;

    #pragma unroll
    for (int t = 0; t < 9; ++t) {
        const float ky = (float)(t/3 - 1);
        const float kx = (float)(t%3 - 1);
        float ys = (float)(i - 1) + ky*s1 + off0;
        float xs = (float)(j - 1) + kx*s2 + off1;
        float y0f = floorf(ys), x0f = floorf(xs);
        float wy = ys - y0f, wx = xs - x0f;
        float vy0 = (y0f        >= 0.f && y0f        <= (float)(Hdim-1)) ? 1.f : 0.f;
        float vy1 = (y0f + 1.f  >= 0.f && y0f + 1.f  <= (float)(Hdim-1)) ? 1.f : 0.f;
        float vx0 = (x0f        >= 0.f && x0f        <= (float)(Wdim-1)) ? 1.f : 0.f;
        float vx1 = (x0f + 1.f  >= 0.f && x0f + 1.f  <= (float)(Wdim-1)) ? 1.f : 0.f;
        float w00 = (1.f-wy)*(1.f-wx)*vy0*vx0;
        float w01 = (1.f-wy)*wx      *vy0*vx1;
        float w10 = wy      *(1.f-wx)*vy1*vx0;
        float w11 = wy      *wx      *vy1*vx1;
        int iy0 = min(max((int)y0f,     0), Hdim-1);
        int iy1 = min(max((int)y0f + 1, 0), Hdim-1);
        int ix0 = min(max((int)x0f,     0), Wdim-1);
        int ix1 = min(max((int)x0f + 1, 0), Wdim-1);
        int i00 = iy0*Wdim + ix0, i01 = iy0*Wdim + ix1;
        int i10 = iy1*Wdim + ix0, i11 = iy1*Wdim + ix1;

        for (int cc = 0; cc < 16; ++cc) {
            int c = c0 + cc;
            const float* p = xb + (size_t)c*HW;
            float v = w00*p[i00] + w01*p[i01] + w10*p[i10] + w11*p[i11];
            const float4* wr4 = reinterpret_cast<const float4*>(g_wT + (c*9 + t)*64);
            #pragma unroll
            for (int q = 0; q < 16; ++q) {
                float4 wv = wr4[q];
                acc[4*q+0] = fmaf(wv.x, v, acc[4*q+0]);
                acc[4*q+1] = fmaf(wv.y, v, acc[4*q+1]);
                acc[4*q+2] = fmaf(wv.z, v, acc[4*q+2]);
                acc[4*q+3] = fmaf(wv.w, v, acc[4*q+3]);
            }
        }
    }

    // Cross-wave (c-chunk) reduction into LDS; stagger start to cut same-address contention.
    #pragma unroll
    for (int q = 0; q < 64; ++q) {
        int qq = (q + wid*16) & 63;
        atomicAdd(&lds[lane*65 + qq], acc[qq]);
    }
    __syncthreads();

    #pragma unroll
    for (int cc = 0; cc < 16; ++cc) {
        int co = wid*16 + cc;
        float val = lds[lane*65 + co] + bias[co];
        out[((size_t)(b*COdim + co)*Hdim + i)*Wdim + (j0 + lane)] = val;
    }
}

extern "C" void kernel_launch(void* const* d_in, const int* in_sizes, int n_in,
                              void* d_out, int out_size, void* d_ws, size_t ws_size,
                              hipStream_t stream) {
    const float* x      = (const float*)d_in[0];
    const float* w_off  = (const float*)d_in[1];
    const float* b_off  = (const float*)d_in[2];
    const float* weight = (const float*)d_in[3];
    const float* bias   = (const float*)d_in[4];
    float* out = (float*)d_out;

    hipLaunchKernelGGL(kt_transpose, dim3(144),  dim3(256), 0, stream, weight);
    hipLaunchKernelGGL(k_offsets,    dim3(256),  dim3(256), 0, stream, x, w_off, b_off);
    hipLaunchKernelGGL(k_deform,     dim3(1024), dim3(256), 0, stream, x, bias, out);
}

// Round 2
// 183.193 us; speedup vs baseline: 2.8308x; 2.8308x over previous
//
#include <hip/hip_runtime.h>

#define Hd 128
#define Wd 128
#define Cd 64
#define COd 64
#define Bd 4
#define HWd (Hd*Wd)
#define KS 18   // 576 / 32 K-steps

typedef __attribute__((ext_vector_type(8))) short  short8;
typedef __attribute__((ext_vector_type(4))) float  f32x4;

// Static device scratch.
__device__ __align__(16) short g_wbf[COd*576];   // bf16 W[co][k], k = t*64 + c
__device__ float4 g_offs[Bd*HWd];                // (off0, off1, s1, s2) per pixel

static __device__ __forceinline__ short f2bf(float v) {
    unsigned u = __float_as_uint(v);
    u += 0x7FFFu + ((u >> 16) & 1u);   // round-to-nearest-even
    return (short)(u >> 16);
}

__global__ __launch_bounds__(256) void kt_prep(const float* __restrict__ weight) {
    int g = blockIdx.x*256 + threadIdx.x;     // 64*576 = 36864
    if (g < COd*576) {
        int co = g / 576, k = g % 576;
        int t = k >> 6, c = k & 63;           // k = t*64 + c
        g_wbf[g] = f2bf(weight[(co*Cd + c)*9 + t]);
    }
}

__global__ __launch_bounds__(256) void k_offsets(const float* __restrict__ x,
                                                 const float* __restrict__ w_off,
                                                 const float* __restrict__ b_off) {
    int gid = blockIdx.x;            // 512 = b*128 + i
    int b = gid >> 7, i = gid & 127;
    int h = threadIdx.x >> 7;        // channel half
    int j = threadIdx.x & 127;

    float a0 = 0.f, a1 = 0.f, a2 = 0.f, a3 = 0.f;
    for (int c = h*32; c < h*32 + 32; ++c) {
        const float* xb = x + (size_t)(b*Cd + c)*HWd;
        const float* wo = w_off + c*9;
        #pragma unroll
        for (int t = 0; t < 9; ++t) {
            int dy = t/3 - 1, dx = t%3 - 1;
            int yy = i + dy, xx = j + dx;
            float v = (yy >= 0 && yy < Hd && xx >= 0 && xx < Wd) ? xb[yy*Wd + xx] : 0.f;
            a0 = fmaf(v, wo[0*Cd*9 + t], a0);
            a1 = fmaf(v, wo[1*Cd*9 + t], a1);
            a2 = fmaf(v, wo[2*Cd*9 + t], a2);
            a3 = fmaf(v, wo[3*Cd*9 + t], a3);
        }
    }
    __shared__ float red[4][128];
    if (h == 1) { red[0][j] = a0; red[1][j] = a1; red[2][j] = a2; red[3][j] = a3; }
    __syncthreads();
    if (h == 0) {
        a0 += red[0][j] + b_off[0];
        a1 += red[1][j] + b_off[1];
        float s1 = fmaxf(a2 + red[2][j] + b_off[2], 0.f) + 1.f;
        float s2 = fmaxf(a3 + red[3][j] + b_off[3], 0.f) + 1.f;
        g_offs[(b*Hd + i)*Wd + j] = make_float4(a0, a1, s1, s2);
    }
}

__global__ __launch_bounds__(256, 4) void k_deform(const float* __restrict__ x,
                                                   const float* __restrict__ bias,
                                                   float* __restrict__ out) {
    __shared__ uint4 lds_b[KS*2*64];   // B-fragments, 36864 B
    int gid = blockIdx.x;              // 2048 = b*512 + i*4 + jq
    int b  = gid >> 9;
    int r  = gid & 511;
    int i  = r >> 2;
    int j0 = (r & 3) << 5;
    int w  = threadIdx.x >> 6;
    int l  = threadIdx.x & 63;
    int pc = l & 15, q = l >> 4;

    // ---- Phase A: sample 32 px x 576 k into LDS in B-fragment order ----
    int nt  = w & 1;                   // px group (16)
    int par = w >> 1;                  // ks parity
    int px  = nt*16 + pc;
    int j   = j0 + px;
    float4 o = g_offs[(b*Hd + i)*Wd + j];
    float off0 = o.x, off1 = o.y, s1 = o.z, s2 = o.w;
    const float* xb = x + (size_t)b*Cd*HWd;

    for (int ks = par; ks < KS; ks += 2) {
        int t = ks >> 1;                       // k = t*64 + c
        int cbase = ((ks & 1) << 5) + q*8;
        float ky = (float)(t/3 - 1), kx = (float)(t%3 - 1);
        float ys = (float)(i - 1) + ky*s1 + off0;
        float xs = (float)(j - 1) + kx*s2 + off1;
        float y0f = floorf(ys), x0f = floorf(xs);
        float wy = ys - y0f, wx = xs - x0f;
        float vy0 = (y0f >=  0.f && y0f <= 127.f) ? 1.f : 0.f;
        float vy1 = (y0f >= -1.f && y0f <= 126.f) ? 1.f : 0.f;
        float vx0 = (x0f >=  0.f && x0f <= 127.f) ? 1.f : 0.f;
        float vx1 = (x0f >= -1.f && x0f <= 126.f) ? 1.f : 0.f;
        float w00 = (1.f-wy)*(1.f-wx)*vy0*vx0, w01 = (1.f-wy)*wx*vy0*vx1;
        float w10 = wy*(1.f-wx)*vy1*vx0,       w11 = wy*wx*vy1*vx1;
        int iy0 = min(max((int)y0f,     0), 127), iy1 = min(max((int)y0f + 1, 0), 127);
        int ix0 = min(max((int)x0f,     0), 127), ix1 = min(max((int)x0f + 1, 0), 127);
        int i00 = iy0*Wd + ix0, i01 = iy0*Wd + ix1;
        int i10 = iy1*Wd + ix0, i11 = iy1*Wd + ix1;

        unsigned pk[4];
        #pragma unroll
        for (int e2 = 0; e2 < 4; ++e2) {
            const float* p0 = xb + (size_t)(cbase + 2*e2    )*HWd;
            const float* p1 = xb + (size_t)(cbase + 2*e2 + 1)*HWd;
            float v0 = w00*p0[i00] + w01*p0[i01] + w10*p0[i10] + w11*p0[i11];
            float v1 = w00*p1[i00] + w01*p1[i01] + w10*p1[i10] + w11*p1[i11];
            pk[e2] = (unsigned)(unsigned short)f2bf(v0)
                   | ((unsigned)(unsigned short)f2bf(v1) << 16);
        }
        lds_b[(ks*2 + nt)*64 + l] = make_uint4(pk[0], pk[1], pk[2], pk[3]);
    }
    __syncthreads();

    // ---- Phase B: 16co x 32px GEMM tile per wave ----
    f32x4 acc0 = {0.f, 0.f, 0.f, 0.f};
    f32x4 acc1 = {0.f, 0.f, 0.f, 0.f};
    const short* wrow = g_wbf + (size_t)(w*16 + pc)*576;
    for (int ks = 0; ks < KS; ++ks) {
        short8 a  = *(const short8*)(wrow + ks*32 + q*8);
        short8 b0 = *(const short8*)&lds_b[(ks*2 + 0)*64 + l];
        short8 b1 = *(const short8*)&lds_b[(ks*2 + 1)*64 + l];
        acc0 = __builtin_amdgcn_mfma_f32_16x16x32_bf16(a, b0, acc0, 0, 0, 0);
        acc1 = __builtin_amdgcn_mfma_f32_16x16x32_bf16(a, b1, acc1, 0, 0, 0);
    }

    // ---- store: D row = co_local = q*4+rr, col = px_local = pc ----
    #pragma unroll
    for (int rr = 0; rr < 4; ++rr) {
        int co = w*16 + q*4 + rr;
        float bco = bias[co];
        size_t base = ((size_t)(b*COd + co)*Hd + i)*Wd + j0;
        out[base + pc]      = acc0[rr] + bco;
        out[base + 16 + pc] = acc1[rr] + bco;
    }
}

extern "C" void kernel_launch(void* const* d_in, const int* in_sizes, int n_in,
                              void* d_out, int out_size, void* d_ws, size_t ws_size,
                              hipStream_t stream) {
    const float* x      = (const float*)d_in[0];
    const float* w_off  = (const float*)d_in[1];
    const float* b_off  = (const float*)d_in[2];
    const float* weight = (const float*)d_in[3];
    const float* bias   = (const float*)d_in[4];
    float* out = (float*)d_out;

    hipLaunchKernelGGL(kt_prep,   dim3(144),  dim3(256), 0, stream, weight);
    hipLaunchKernelGGL(k_offsets, dim3(512),  dim3(256), 0, stream, x, w_off, b_off);
    hipLaunchKernelGGL(k_deform,  dim3(2048), dim3(256), 0, stream, x, bias, out);
}

// Round 3
// 76.081 us; speedup vs baseline: 6.8163x; 2.4079x over previous
//
#include <hip/hip_runtime.h>

#define Hd 128
#define Wd 128
#define Cd 64
#define COd 64
#define Bd 4
#define HWd (Hd*Wd)
#define KS 18   // 576 / 32 K-steps

typedef __attribute__((ext_vector_type(8))) short  short8;
typedef __attribute__((ext_vector_type(4))) float  f32x4;

// Static device scratch.
__device__ __align__(16) short g_wbf[COd*576];              // bf16 W[co][k], k = t*64 + c
__device__ float4 g_offs[Bd*HWd];                           // (off0, off1, s1, s2)
__device__ __align__(16) unsigned short g_xt[(size_t)Bd*HWd*Cd]; // bf16 NHWC x

static __device__ __forceinline__ unsigned short f2bf(float v) {
    unsigned u = __float_as_uint(v);
    u += 0x7FFFu + ((u >> 16) & 1u);   // RNE
    return (unsigned short)(u >> 16);
}
static __device__ __forceinline__ float bflo(unsigned u) { return __uint_as_float(u << 16); }
static __device__ __forceinline__ float bfhi(unsigned u) { return __uint_as_float(u & 0xFFFF0000u); }

__global__ __launch_bounds__(256) void kt_prep(const float* __restrict__ weight) {
    int g = blockIdx.x*256 + threadIdx.x;     // 64*576
    if (g < COd*576) {
        int co = g / 576, k = g % 576;
        int t = k >> 6, c = k & 63;           // k = t*64 + c
        g_wbf[g] = (short)f2bf(weight[(co*Cd + c)*9 + t]);
    }
}

// x[B][C][H][W] fp32 -> g_xt[B][H][W][C] bf16
__global__ __launch_bounds__(256) void k_nhwc(const float* __restrict__ x) {
    int gid = blockIdx.x;               // 512 = b*128 + y
    int b = gid >> 7, y = gid & 127;
    int px = threadIdx.x & 127;
    int h  = threadIdx.x >> 7;          // 32-channel half
    const float* xb = x + (size_t)b*Cd*HWd + y*Wd + px;
    unsigned short* ob = g_xt + ((size_t)(b*HWd) + y*Wd + px)*Cd + h*32;
    #pragma unroll
    for (int oct = 0; oct < 4; ++oct) {
        unsigned pk[4];
        #pragma unroll
        for (int e = 0; e < 4; ++e) {
            float v0 = xb[(size_t)(h*32 + oct*8 + 2*e    )*HWd];
            float v1 = xb[(size_t)(h*32 + oct*8 + 2*e + 1)*HWd];
            pk[e] = (unsigned)f2bf(v0) | ((unsigned)f2bf(v1) << 16);
        }
        *(uint4*)(ob + oct*8) = make_uint4(pk[0], pk[1], pk[2], pk[3]);
    }
}

__global__ __launch_bounds__(256) void k_offsets(const float* __restrict__ w_off,
                                                 const float* __restrict__ b_off) {
    __shared__ float red[4][128];
    int gid = blockIdx.x;               // 512 = b*128 + i
    int b = gid >> 7, i = gid & 127;
    int j = threadIdx.x & 127;
    int h = threadIdx.x >> 7;           // 32-channel half (wave-uniform)
    float a0 = 0.f, a1 = 0.f, a2 = 0.f, a3 = 0.f;
    const unsigned short* xb = g_xt + (size_t)b*HWd*Cd;
    #pragma unroll
    for (int dy = -1; dy <= 1; ++dy) {
        int yy = i + dy;
        if (yy < 0 || yy > 127) continue;
        #pragma unroll
        for (int dx = -1; dx <= 1; ++dx) {
            int xx = j + dx;
            if (xx < 0 || xx > 127) continue;
            int t = (dy + 1)*3 + (dx + 1);
            const unsigned short* p = xb + (size_t)(yy*Wd + xx)*Cd + h*32;
            #pragma unroll
            for (int oct = 0; oct < 4; ++oct) {
                uint4 u = *(const uint4*)(p + oct*8);
                unsigned aa[4] = {u.x, u.y, u.z, u.w};
                #pragma unroll
                for (int e = 0; e < 4; ++e) {
                    int c = h*32 + oct*8 + 2*e;
                    float v0 = bflo(aa[e]), v1 = bfhi(aa[e]);
                    a0 = fmaf(v0, w_off[(0*Cd + c)*9 + t], a0);
                    a0 = fmaf(v1, w_off[(0*Cd + c + 1)*9 + t], a0);
                    a1 = fmaf(v0, w_off[(1*Cd + c)*9 + t], a1);
                    a1 = fmaf(v1, w_off[(1*Cd + c + 1)*9 + t], a1);
                    a2 = fmaf(v0, w_off[(2*Cd + c)*9 + t], a2);
                    a2 = fmaf(v1, w_off[(2*Cd + c + 1)*9 + t], a2);
                    a3 = fmaf(v0, w_off[(3*Cd + c)*9 + t], a3);
                    a3 = fmaf(v1, w_off[(3*Cd + c + 1)*9 + t], a3);
                }
            }
        }
    }
    if (h == 1) { red[0][j] = a0; red[1][j] = a1; red[2][j] = a2; red[3][j] = a3; }
    __syncthreads();
    if (h == 0) {
        a0 += red[0][j] + b_off[0];
        a1 += red[1][j] + b_off[1];
        float s1 = fmaxf(a2 + red[2][j] + b_off[2], 0.f) + 1.f;
        float s2 = fmaxf(a3 + red[3][j] + b_off[3], 0.f) + 1.f;
        g_offs[(b*Hd + i)*Wd + j] = make_float4(a0, a1, s1, s2);
    }
}

__global__ __launch_bounds__(256, 4) void k_deform(const float* __restrict__ bias,
                                                   float* __restrict__ out) {
    __shared__ uint4 lds_b[KS*2*64];    // 36864 B
    int gid = blockIdx.x;               // 2048 = b*512 + i*4 + jq
    int b  = gid >> 9;
    int r  = gid & 511;
    int i  = r >> 2;
    int j0 = (r & 3) << 5;
    int w  = threadIdx.x >> 6;
    int l  = threadIdx.x & 63;

    // ---- Phase A: lanes = 8 px x 8 channel-octets; full-line gathers ----
    int px8 = l >> 3, oct = l & 7;
    int pxl = w*8 + px8;                // 0..31
    int j   = j0 + pxl;
    int nt  = pxl >> 4, pc = pxl & 15;
    int q   = oct & 3;
    int slot = (pc ^ (q << 1)) + (q << 4);   // bank swizzle

    float4 o = g_offs[(b*Hd + i)*Wd + j];
    float off0 = o.x, off1 = o.y, s1 = o.z, s2 = o.w;
    const unsigned short* xb = g_xt + (size_t)b*HWd*Cd;

    #pragma unroll 3
    for (int t = 0; t < 9; ++t) {
        float ys = (float)(i - 1) + (float)(t/3 - 1)*s1 + off0;
        float xs = (float)(j - 1) + (float)(t%3 - 1)*s2 + off1;
        float y0f = floorf(ys), x0f = floorf(xs);
        float wy = ys - y0f, wx = xs - x0f;
        float vy0 = (y0f >=  0.f && y0f <= 127.f) ? 1.f : 0.f;
        float vy1 = (y0f >= -1.f && y0f <= 126.f) ? 1.f : 0.f;
        float vx0 = (x0f >=  0.f && x0f <= 127.f) ? 1.f : 0.f;
        float vx1 = (x0f >= -1.f && x0f <= 126.f) ? 1.f : 0.f;
        float w00 = (1.f-wy)*(1.f-wx)*vy0*vx0, w01 = (1.f-wy)*wx*vy0*vx1;
        float w10 = wy*(1.f-wx)*vy1*vx0,       w11 = wy*wx*vy1*vx1;
        int iy0 = min(max((int)y0f,     0), 127), iy1 = min(max((int)y0f + 1, 0), 127);
        int ix0 = min(max((int)x0f,     0), 127), ix1 = min(max((int)x0f + 1, 0), 127);
        const unsigned short* p00 = xb + (size_t)(iy0*Wd + ix0)*Cd + oct*8;
        const unsigned short* p01 = xb + (size_t)(iy0*Wd + ix1)*Cd + oct*8;
        const unsigned short* p10 = xb + (size_t)(iy1*Wd + ix0)*Cd + oct*8;
        const unsigned short* p11 = xb + (size_t)(iy1*Wd + ix1)*Cd + oct*8;
        uint4 u00 = *(const uint4*)p00, u01 = *(const uint4*)p01;
        uint4 u10 = *(const uint4*)p10, u11 = *(const uint4*)p11;
        unsigned a00[4] = {u00.x,u00.y,u00.z,u00.w}, a01[4] = {u01.x,u01.y,u01.z,u01.w};
        unsigned a10[4] = {u10.x,u10.y,u10.z,u10.w}, a11[4] = {u11.x,u11.y,u11.z,u11.w};
        unsigned pk[4];
        #pragma unroll
        for (int e = 0; e < 4; ++e) {
            float vlo = w00*bflo(a00[e]) + w01*bflo(a01[e]) + w10*bflo(a10[e]) + w11*bflo(a11[e]);
            float vhi = w00*bfhi(a00[e]) + w01*bfhi(a01[e]) + w10*bfhi(a10[e]) + w11*bfhi(a11[e]);
            pk[e] = (unsigned)f2bf(vlo) | ((unsigned)f2bf(vhi) << 16);
        }
        int ks = 2*t + (oct >> 2);
        lds_b[(ks*2 + nt)*64 + slot] = make_uint4(pk[0], pk[1], pk[2], pk[3]);
    }
    __syncthreads();

    // ---- Phase B: 16co x 32px GEMM tile per wave ----
    f32x4 acc0 = {0.f,0.f,0.f,0.f};
    f32x4 acc1 = {0.f,0.f,0.f,0.f};
    int pcB = l & 15, qB = l >> 4;
    int physl = (pcB ^ (qB << 1)) + (qB << 4);
    const short* wrow = g_wbf + (size_t)(w*16 + pcB)*576;
    for (int ks = 0; ks < KS; ++ks) {
        short8 a  = *(const short8*)(wrow + ks*32 + qB*8);
        short8 b0 = *(const short8*)&lds_b[(ks*2 + 0)*64 + physl];
        short8 b1 = *(const short8*)&lds_b[(ks*2 + 1)*64 + physl];
        acc0 = __builtin_amdgcn_mfma_f32_16x16x32_bf16(a, b0, acc0, 0, 0, 0);
        acc1 = __builtin_amdgcn_mfma_f32_16x16x32_bf16(a, b1, acc1, 0, 0, 0);
    }

    // ---- store: D row = co_local = qB*4+rr, col = pcB ----
    #pragma unroll
    for (int rr = 0; rr < 4; ++rr) {
        int co = w*16 + qB*4 + rr;
        float bco = bias[co];
        size_t base = ((size_t)(b*COd + co)*Hd + i)*Wd + j0;
        out[base + pcB]      = acc0[rr] + bco;
        out[base + 16 + pcB] = acc1[rr] + bco;
    }
}

extern "C" void kernel_launch(void* const* d_in, const int* in_sizes, int n_in,
                              void* d_out, int out_size, void* d_ws, size_t ws_size,
                              hipStream_t stream) {
    const float* x      = (const float*)d_in[0];
    const float* w_off  = (const float*)d_in[1];
    const float* b_off  = (const float*)d_in[2];
    const float* weight = (const float*)d_in[3];
    const float* bias   = (const float*)d_in[4];
    float* out = (float*)d_out;

    hipLaunchKernelGGL(k_nhwc,    dim3(512),  dim3(256), 0, stream, x);
    hipLaunchKernelGGL(kt_prep,   dim3(144),  dim3(256), 0, stream, weight);
    hipLaunchKernelGGL(k_offsets, dim3(512),  dim3(256), 0, stream, w_off, b_off);
    hipLaunchKernelGGL(k_deform,  dim3(2048), dim3(256), 0, stream, bias, out);
}